// Round 13
// baseline (434.518 us; speedup 1.0000x reference)
//
#include <hip/hip_runtime.h>
#include <stdint.h>

#define N_NODES 32768
#define N_EDGES 524288
#define NODE_MASK (N_NODES - 1)

typedef __attribute__((ext_vector_type(8))) short bf16x8;
typedef __attribute__((ext_vector_type(4))) float f32x4;
typedef __attribute__((ext_vector_type(8))) _Float16 f16x8;
typedef unsigned short ushort_t;

__device__ __forceinline__ ushort_t f2b(float f) {  // f32 -> bf16 RNE
  uint32_t u = __float_as_uint(f);
  return (ushort_t)((u + 0x7FFFu + ((u >> 16) & 1u)) >> 16);
}
__device__ __forceinline__ float b2f(uint32_t lo16) {
  return __uint_as_float(lo16 << 16);
}

// split f32[8] -> (hi trunc, lo RNE) bf16x8 planes
__device__ __forceinline__ void split8(const float* __restrict__ p,
                                       bf16x8* H, bf16x8* L) {
  bf16x8 h, lo;
#pragma unroll
  for (int i = 0; i < 8; ++i) {
    float x = p[i];
    uint32_t u = __float_as_uint(x);
    ushort_t hb = (ushort_t)(u >> 16);                 // truncation split
    float r = x - __uint_as_float((uint32_t)hb << 16); // exact residual
    h[i] = (short)hb;
    lo[i] = (short)f2b(r);
  }
  *H = h; *L = lo;
}

// ---------------- threefry2x32 (Threefry-20, partitionable mode) ------------
__device__ __forceinline__ uint32_t rotl32(uint32_t v, int r) {
  return (v << r) | (v >> (32 - r));
}

__device__ __forceinline__ void threefry2x32(uint32_t k0, uint32_t k1,
                                             uint32_t x0, uint32_t x1,
                                             uint32_t* o0, uint32_t* o1) {
  uint32_t k2 = k0 ^ k1 ^ 0x1BD11BDAu;
  x0 += k0; x1 += k1;
  x0 += x1; x1 = rotl32(x1, 13); x1 ^= x0;
  x0 += x1; x1 = rotl32(x1, 15); x1 ^= x0;
  x0 += x1; x1 = rotl32(x1, 26); x1 ^= x0;
  x0 += x1; x1 = rotl32(x1,  6); x1 ^= x0;
  x0 += k1; x1 += k2 + 1u;
  x0 += x1; x1 = rotl32(x1, 17); x1 ^= x0;
  x0 += x1; x1 = rotl32(x1, 29); x1 ^= x0;
  x0 += x1; x1 = rotl32(x1, 16); x1 ^= x0;
  x0 += x1; x1 = rotl32(x1, 24); x1 ^= x0;
  x0 += k2; x1 += k0 + 2u;
  x0 += x1; x1 = rotl32(x1, 13); x1 ^= x0;
  x0 += x1; x1 = rotl32(x1, 15); x1 ^= x0;
  x0 += x1; x1 = rotl32(x1, 26); x1 ^= x0;
  x0 += x1; x1 = rotl32(x1,  6); x1 ^= x0;
  x0 += k0; x1 += k1 + 3u;
  x0 += x1; x1 = rotl32(x1, 17); x1 ^= x0;
  x0 += x1; x1 = rotl32(x1, 29); x1 ^= x0;
  x0 += x1; x1 = rotl32(x1, 16); x1 ^= x0;
  x0 += x1; x1 = rotl32(x1, 24); x1 ^= x0;
  x0 += k1; x1 += k2 + 4u;
  x0 += x1; x1 = rotl32(x1, 13); x1 ^= x0;
  x0 += x1; x1 = rotl32(x1, 15); x1 ^= x0;
  x0 += x1; x1 = rotl32(x1, 26); x1 ^= x0;
  x0 += x1; x1 = rotl32(x1,  6); x1 ^= x0;
  x0 += k2; x1 += k0 + 5u;
  *o0 = x0; *o1 = x1;
}

__device__ __forceinline__ float bits_to_normal(uint32_t b) {
  uint32_t fb = (b >> 9) | 0x3F800000u;
  float f = __uint_as_float(fb) - 1.0f;          // [0,1)
  const float LO = -0.99999994f;
  float u = f * 2.0f + LO;
  u = fmaxf(LO, u);
  double zd = 1.4142135623730951 * erfinv((double)u);
  return (float)zd;
}

// ---------------- zero helper ------------------------------------------------
__global__ void k_zero(int* __restrict__ p, int n) {
  for (int i = blockIdx.x * blockDim.x + threadIdx.x; i < n;
       i += gridDim.x * blockDim.x)
    p[i] = 0;
}

// ---------------- CSR build (edge_index int32) ------------------------------
__global__ void k_hist(const int* __restrict__ ei, int* __restrict__ counts) {
  for (int e = blockIdx.x * blockDim.x + threadIdx.x; e < N_EDGES;
       e += gridDim.x * blockDim.x)
    atomicAdd(&counts[ei[N_EDGES + e] & NODE_MASK], 1);
}

// scan + zero counts (cursor reuse) in one launch
__global__ __launch_bounds__(1024) void k_scan(int* __restrict__ counts,
                                               int* __restrict__ row_ptr) {
  __shared__ int part[1024];
  int t = threadIdx.x;
  const int CH = N_NODES / 1024;  // 32
  int base = t * CH;
  int s = 0;
  for (int i = 0; i < CH; ++i) s += counts[base + i];
  part[t] = s;
  __syncthreads();
  for (int off = 1; off < 1024; off <<= 1) {
    int add = (t >= off) ? part[t - off] : 0;
    __syncthreads();
    part[t] += add;
    __syncthreads();
  }
  int run = (t == 0) ? 0 : part[t - 1];
  for (int i = 0; i < CH; ++i) { row_ptr[base + i] = run; run += counts[base + i]; }
  if (t == 1023) row_ptr[N_NODES] = run;
  __syncthreads();
  for (int i = t; i < N_NODES; i += 1024) counts[i] = 0;  // cursor init
}

__global__ void k_fill(const int* __restrict__ ei, const int* __restrict__ row_ptr,
                       int* __restrict__ cursor, int* __restrict__ srcs) {
  for (int e = blockIdx.x * blockDim.x + threadIdx.x; e < N_EDGES;
       e += gridDim.x * blockDim.x) {
    int d = ei[N_EDGES + e] & NODE_MASK;
    int pos = row_ptr[d] + atomicAdd(&cursor[d], 1);
    srcs[pos] = ei[e] & NODE_MASK;
  }
}

// ---------------- merged prep: Wc combine + whh split + zgen ----------------
// Wc[L][c][k] = sum_j G[L][k][j]*w_ih[c][j]  (hi/lo bf16 planes)
__global__ __launch_bounds__(256) void k_prep(
    const float* __restrict__ G, const float* __restrict__ w_ih,
    const float* __restrict__ w_hh,
    ushort_t* __restrict__ WcH, ushort_t* __restrict__ WcL,
    ushort_t* __restrict__ whhH, ushort_t* __restrict__ whhL,
    float* __restrict__ z) {
  int i = blockIdx.x * 256 + threadIdx.x;
  if (i < 4 * 384 * 128) {
    int L = i / (384 * 128), r = i % (384 * 128);
    int c = r >> 7, k = r & 127;
    const float* g  = G + L * 16384 + k * 128;
    const float* wv = w_ih + c * 128;
    float acc = 0.f;
#pragma unroll 8
    for (int j = 0; j < 128; ++j) acc += g[j] * wv[j];
    ushort_t h = f2b(acc);
    WcH[i] = h; WcL[i] = f2b(acc - b2f(h));
  }
  if (i < 384 * 128) {
    float b = w_hh[i];
    ushort_t bh = f2b(b);
    whhH[i] = bh; whhL[i] = f2b(b - b2f(bh));
  }
  if (i < 32640) {
    uint32_t o0, o1;
    threefry2x32(0u, 123u, 0u, (uint32_t)i, &o0, &o1);
    z[i] = bits_to_normal(o0 ^ o1);
  }
}

// ---------------- lin0: hf (f32) + h16 (f16 shadow), padded to 128 ----------
__global__ __launch_bounds__(256) void k_lin0(const float* __restrict__ x,
                                              const float* __restrict__ w,
                                              float* __restrict__ hf,
                                              _Float16* __restrict__ h16) {
  __shared__ float sw[64][33];
  __shared__ float sx[4][32];
  int t = threadIdx.x;
  for (int e = t; e < 64 * 32; e += 256) sw[e >> 5][e & 31] = w[e];
  int node0 = blockIdx.x * 4;
  if (t < 128) sx[t >> 5][t & 31] = x[node0 * 32 + t];
  __syncthreads();
  int c = t & 63, nl = t >> 6;
  float acc = 0.f;
#pragma unroll
  for (int k = 0; k < 32; ++k) acc += sx[nl][k] * sw[c][k];
  float s = 1.f / (1.f + expf(-acc));
  int n = node0 + nl;
  hf[n * 128 + c] = s;
  hf[n * 128 + 64 + c] = 0.f;
  h16[n * 128 + c] = (_Float16)s;
  h16[n * 128 + 64 + c] = (_Float16)0.f;
}

// ---------------- segment-sum gather: 16B/lane, 4 edges/instr, f32 out ------
__global__ void k_agg(const _Float16* __restrict__ h16,
                      float* __restrict__ mg,
                      const int* __restrict__ row_ptr, const int* __restrict__ srcs) {
  int wid = (blockIdx.x * blockDim.x + threadIdx.x) >> 6;
  int lane = threadIdx.x & 63;
  if (wid >= N_NODES) return;
  int cg = lane & 15, eg = lane >> 4;
  int beg = row_ptr[wid], end = row_ptr[wid + 1];
  float acc[8];
#pragma unroll
  for (int i = 0; i < 8; ++i) acc[i] = 0.f;
  for (int e = beg + eg; e < end; e += 4) {
    int s = srcs[e] & NODE_MASK;
    f16x8 v = *(const f16x8*)&h16[s * 128 + cg * 8];
#pragma unroll
    for (int i = 0; i < 8; ++i) acc[i] += (float)v[i];
  }
#pragma unroll
  for (int i = 0; i < 8; ++i) {
    acc[i] += __shfl_xor(acc[i], 16);
    acc[i] += __shfl_xor(acc[i], 32);
  }
  if (eg == 0) {
    float4 lo = make_float4(acc[0], acc[1], acc[2], acc[3]);
    float4 hi = make_float4(acc[4], acc[5], acc[6], acc[7]);
    *(float4*)&mg[wid * 128 + cg * 8] = lo;
    *(float4*)&mg[wid * 128 + cg * 8 + 4] = hi;
  }
}

// ---------------- fused GRU via 3-term split MFMA, 32 nodes/wave ------------
// Each wave owns TWO 16-node tiles so every B-fragment LDS read feeds 36
// MFMAs (halves LDS-read volume vs 1 tile). Weights staged per ct via
// global_load_lds (linear dest, pre-swizzled source; read applies same XOR).
__global__ __launch_bounds__(256, 2) void k_gru_mfma(
    const float* __restrict__ mg,
    float* __restrict__ hf, _Float16* __restrict__ h16,
    const ushort_t* __restrict__ WcH, const ushort_t* __restrict__ WcL,
    const ushort_t* __restrict__ whhH, const ushort_t* __restrict__ whhL,
    const float* __restrict__ b_ih, const float* __restrict__ b_hh,
    int writeShadow) {
  __shared__ __align__(16) char smem[49152];  // 12 slices x 4 KB
  int t = threadIdx.x;
  int w = t >> 6, l = t & 63;
  int node0 = blockIdx.x * 128 + w * 32;      // wave: nodes node0..node0+31
  int ar = l & 15, hi = l >> 4, ak = hi * 8;
  bf16x8 amH[2][4], amL[2][4], ahH[2][4], ahL[2][4];
#pragma unroll
  for (int tl = 0; tl < 2; ++tl)
#pragma unroll
    for (int kk = 0; kk < 4; ++kk) {
      int o = (node0 + tl * 16 + ar) * 128 + kk * 32 + ak;
      split8(&mg[o], &amH[tl][kk], &amL[tl][kk]);
      split8(&hf[o], &ahH[tl][kk], &ahL[tl][kk]);
    }
  // per-lane pre-swizzled global source pointers (12 x 1KB wave chunks / ct)
  const ushort_t* pq[12];
#pragma unroll
  for (int q = 0; q < 12; ++q) {
    int i = (q * 4 + w) * 64 + l;          // linear granule index in 48 KB
    int s = i >> 8, r = (i >> 4) & 15, gl = i & 15;
    int gsrc = gl ^ (r & 7);               // inverse of read-side XOR
    int mtx = s / 6, rem = s % 6, gate = rem >> 1, plane = rem & 1;
    const ushort_t* base = mtx ? (plane ? whhL : whhH) : (plane ? WcL : WcH);
    pq[q] = base + (gate * 128 + r) * 128 + gsrc * 8;
  }
  const char* lds = (const char*)smem;
  for (int ct = 0; ct < 8; ++ct) {
    int c0 = ct * 16;
    // async stage this ct's 48 KB of weights
#pragma unroll
    for (int q = 0; q < 12; ++q) {
      __builtin_amdgcn_global_load_lds(
          (const __attribute__((address_space(1))) void*)(pq[q] + c0 * 128),
          (__attribute__((address_space(3))) void*)(smem + (q * 4 + w) * 1024),
          16, 0, 0);
    }
    int col = c0 + ar;
    float hp[2][4];
#pragma unroll
    for (int tl = 0; tl < 2; ++tl)
#pragma unroll
      for (int j = 0; j < 4; ++j)
        hp[tl][j] = hf[(node0 + tl * 16 + hi * 4 + j) * 128 + col];
    __syncthreads();  // staging landed
    f32x4 air[2], aiz[2], ain[2], ahr[2], ahz[2], ahn[2];
#pragma unroll
    for (int tl = 0; tl < 2; ++tl) {
      air[tl] = (f32x4){0.f,0.f,0.f,0.f}; aiz[tl] = air[tl]; ain[tl] = air[tl];
      ahr[tl] = air[tl]; ahz[tl] = air[tl]; ahn[tl] = air[tl];
    }
    int rbase = ar * 256;
    int rsw = (ar & 7) << 4;
#pragma unroll
    for (int kk = 0; kk < 4; ++kk) {
      int bin = rbase + ((kk * 64 + hi * 16) ^ rsw);
      bf16x8 B0  = *(const bf16x8*)(lds + 0 * 4096 + bin);
      bf16x8 B1  = *(const bf16x8*)(lds + 1 * 4096 + bin);
      bf16x8 B2  = *(const bf16x8*)(lds + 2 * 4096 + bin);
      bf16x8 B3  = *(const bf16x8*)(lds + 3 * 4096 + bin);
      bf16x8 B4  = *(const bf16x8*)(lds + 4 * 4096 + bin);
      bf16x8 B5  = *(const bf16x8*)(lds + 5 * 4096 + bin);
      bf16x8 B6  = *(const bf16x8*)(lds + 6 * 4096 + bin);
      bf16x8 B7  = *(const bf16x8*)(lds + 7 * 4096 + bin);
      bf16x8 B8  = *(const bf16x8*)(lds + 8 * 4096 + bin);
      bf16x8 B9  = *(const bf16x8*)(lds + 9 * 4096 + bin);
      bf16x8 B10 = *(const bf16x8*)(lds + 10 * 4096 + bin);
      bf16x8 B11 = *(const bf16x8*)(lds + 11 * 4096 + bin);
#pragma unroll
      for (int tl = 0; tl < 2; ++tl) {
        air[tl] = __builtin_amdgcn_mfma_f32_16x16x32_bf16(amH[tl][kk], B0,  air[tl], 0, 0, 0);
        air[tl] = __builtin_amdgcn_mfma_f32_16x16x32_bf16(amH[tl][kk], B1,  air[tl], 0, 0, 0);
        air[tl] = __builtin_amdgcn_mfma_f32_16x16x32_bf16(amL[tl][kk], B0,  air[tl], 0, 0, 0);
        aiz[tl] = __builtin_amdgcn_mfma_f32_16x16x32_bf16(amH[tl][kk], B2,  aiz[tl], 0, 0, 0);
        aiz[tl] = __builtin_amdgcn_mfma_f32_16x16x32_bf16(amH[tl][kk], B3,  aiz[tl], 0, 0, 0);
        aiz[tl] = __builtin_amdgcn_mfma_f32_16x16x32_bf16(amL[tl][kk], B2,  aiz[tl], 0, 0, 0);
        ain[tl] = __builtin_amdgcn_mfma_f32_16x16x32_bf16(amH[tl][kk], B4,  ain[tl], 0, 0, 0);
        ain[tl] = __builtin_amdgcn_mfma_f32_16x16x32_bf16(amH[tl][kk], B5,  ain[tl], 0, 0, 0);
        ain[tl] = __builtin_amdgcn_mfma_f32_16x16x32_bf16(amL[tl][kk], B4,  ain[tl], 0, 0, 0);
        ahr[tl] = __builtin_amdgcn_mfma_f32_16x16x32_bf16(ahH[tl][kk], B6,  ahr[tl], 0, 0, 0);
        ahr[tl] = __builtin_amdgcn_mfma_f32_16x16x32_bf16(ahH[tl][kk], B7,  ahr[tl], 0, 0, 0);
        ahr[tl] = __builtin_amdgcn_mfma_f32_16x16x32_bf16(ahL[tl][kk], B6,  ahr[tl], 0, 0, 0);
        ahz[tl] = __builtin_amdgcn_mfma_f32_16x16x32_bf16(ahH[tl][kk], B8,  ahz[tl], 0, 0, 0);
        ahz[tl] = __builtin_amdgcn_mfma_f32_16x16x32_bf16(ahH[tl][kk], B9,  ahz[tl], 0, 0, 0);
        ahz[tl] = __builtin_amdgcn_mfma_f32_16x16x32_bf16(ahL[tl][kk], B8,  ahz[tl], 0, 0, 0);
        ahn[tl] = __builtin_amdgcn_mfma_f32_16x16x32_bf16(ahH[tl][kk], B10, ahn[tl], 0, 0, 0);
        ahn[tl] = __builtin_amdgcn_mfma_f32_16x16x32_bf16(ahH[tl][kk], B11, ahn[tl], 0, 0, 0);
        ahn[tl] = __builtin_amdgcn_mfma_f32_16x16x32_bf16(ahL[tl][kk], B10, ahn[tl], 0, 0, 0);
      }
    }
    float bir = b_ih[col], biz = b_ih[128 + col], bin = b_ih[256 + col];
    float bhr = b_hh[col], bhz = b_hh[128 + col], bhn = b_hh[256 + col];
#pragma unroll
    for (int tl = 0; tl < 2; ++tl)
#pragma unroll
      for (int j = 0; j < 4; ++j) {
        int idx = (node0 + tl * 16 + hi * 4 + j) * 128 + col;
        float gr = air[tl][j] + bir + ahr[tl][j] + bhr;
        float gz = aiz[tl][j] + biz + ahz[tl][j] + bhz;
        float r  = 1.f / (1.f + expf(-gr));
        float zg = 1.f / (1.f + expf(-gz));
        float nn = tanhf(ain[tl][j] + bin + r * (ahn[tl][j] + bhn));
        float hn = (1.f - zg) * nn + zg * hp[tl][j];
        hf[idx] = hn;
        if (writeShadow) h16[idx] = (_Float16)hn;
      }
    __syncthreads();  // all LDS reads done before next ct restages
  }
}

// ---------------- heads (f32 hf) ---------------------------------------------
__global__ __launch_bounds__(256) void k_musig(const float* __restrict__ hf,
                                               const float* __restrict__ w1,
                                               const float* __restrict__ b1,
                                               const float* __restrict__ w2,
                                               const float* __restrict__ b2,
                                               float* __restrict__ mu,
                                               float* __restrict__ sigma) {
  int t = threadIdx.x;
  int lane = t & 63, wv = t >> 6;
  int n = blockIdx.x * 4 + wv;
  float2 hv = *(const float2*)&hf[n * 128 + lane * 2];
  hv.x = fmaxf(hv.x, 0.f); hv.y = fmaxf(hv.y, 0.f);
  float2 w1v = *(const float2*)&w1[lane * 2];
  float2 w2v = *(const float2*)&w2[lane * 2];
  float a = hv.x * w1v.x + hv.y * w1v.y;
  float b = hv.x * w2v.x + hv.y * w2v.y;
#pragma unroll
  for (int off = 32; off > 0; off >>= 1) {
    a += __shfl_down(a, off);
    b += __shfl_down(b, off);
  }
  if (lane == 0) {
    mu[n] = a + b1[0];
    float v = b + b2[0];
    sigma[n] = fmaxf(v, 0.f) + log1pf(expf(-fabsf(v)));
  }
}

// ---------------- sampler (fp64 internal): analytic Cholesky ----------------
__device__ __forceinline__ double dscan_incl(double v, volatile double* buf, int i,
                                             double* tot) {
  buf[i] = v;
  __syncthreads();
#pragma unroll
  for (int off = 1; off < 256; off <<= 1) {
    double add = (i >= off) ? buf[i - off] : 0.0;
    __syncthreads();
    buf[i] += add;
    __syncthreads();
  }
  double incl = buf[i];
  *tot = buf[255];
  __syncthreads();
  return incl;
}

__global__ __launch_bounds__(256) void k_sample(const float* __restrict__ mu,
                                                const float* __restrict__ sigma,
                                                const float* __restrict__ zbuf,
                                                float* __restrict__ out) {
  __shared__ double buf[256];
  __shared__ double lastd[2];
  int g = blockIdx.x, i = threadIdx.x;
  int n = (g << 8) + i;
  double sig = (double)sigma[n], muv = (double)mu[n];
  bool isLast = (i == 255);
  if (isLast) { lastd[0] = sig; lastd[1] = muv; }
  double s   = isLast ? 0.0 : sig;
  double mui = isLast ? 0.0 : muv;
  double tS, tM, tY, tX;
  double inclS = dscan_incl(s, buf, i, &tS);
  dscan_incl(mui, buf, i, &tM);
  double sigLast = lastd[0], muLast = lastd[1];
  double denom = tS + sigLast;
  double c = -muLast / sigLast;
  double pre = inclS - s;
  double suffix  = denom - pre;
  double suffix1 = suffix - s;
  double sigL = isLast ? 0.0 : sqrt(s * suffix1 / suffix);
  double cL   = isLast ? 0.0 : (-s / (suffix * sigL));
  double zv   = isLast ? 0.0 : (double)zbuf[g * 255 + i];
  double y = cL * zv;
  double inclY = dscan_incl(y, buf, i, &tY);
  double Pz = inclY - y;
  double rm = s * c + mui - s * (c * tS + tM) / denom;
  double X = rm + s * Pz + sigL * zv;
  if (isLast) X = 0.0;
  dscan_incl(X, buf, i, &tX);
  out[n] = (float)(isLast ? (0.0 - tX) : X);
}

// ---------------------------------------------------------------------------
extern "C" void kernel_launch(void* const* d_in, const int* in_sizes, int n_in,
                              void* d_out, int out_size, void* d_ws, size_t ws_size,
                              hipStream_t stream) {
  const float* x      = (const float*)d_in[0];
  const float* lin0_w = (const float*)d_in[1];
  const float* ggc_w  = (const float*)d_in[2];
  const float* w_ih   = (const float*)d_in[3];
  const float* w_hh   = (const float*)d_in[4];
  const float* b_ih   = (const float*)d_in[5];
  const float* b_hh   = (const float*)d_in[6];
  const float* lin1_w = (const float*)d_in[7];
  const float* lin1_b = (const float*)d_in[8];
  const float* lin2_w = (const float*)d_in[9];
  const float* lin2_b = (const float*)d_in[10];
  const int*   ei     = (const int*)d_in[11];
  float* out = (float*)d_out;

  char* ws = (char*)d_ws;
  float*    hf     = (float*)   (ws + 0);          // 16 MB (f32 master h)
  _Float16* h16    = (_Float16*)(ws + 16777216);   // 8 MB (f16 gather shadow)
  float*    mg     = (float*)   (ws + 25165824);   // 16 MB (f32 hagg)
  ushort_t* WcH    = (ushort_t*)(ws + 41943040);   // 384 KB (4 layers)
  ushort_t* WcL    = (ushort_t*)(ws + 42336256);   // 384 KB
  ushort_t* whhH   = (ushort_t*)(ws + 42729472);   // 96 KB
  ushort_t* whhL   = (ushort_t*)(ws + 42827776);   // 96 KB
  float*    zbuf   = (float*)   (ws + 42926080);   // 128 KB [counts aliases]
  float*    mu     = (float*)   (ws + 43057152);   // 128 KB
  float*    sigma  = (float*)   (ws + 43188224);   // 128 KB
  int*      row_ptr= (int*)     (ws + 43319296);   // 128.5 KB slot
  int*      srcs   = (int*)     (ws + 43450880);   // 2 MB -> ends 45548032
  int*      counts = (int*)zbuf;                   // alias: CSR before k_prep z
  const size_t WS_NEEDED = 45548032;               // < proven 53477888
  if (ws_size < WS_NEEDED) return;

  // CSR build (counts aliases zbuf; zgen output written later by k_prep)
  k_zero<<<32, 256, 0, stream>>>(counts, N_NODES);
  k_hist<<<1024, 256, 0, stream>>>(ei, counts);
  k_scan<<<1, 1024, 0, stream>>>(counts, row_ptr);   // also re-zeros counts
  k_fill<<<1024, 256, 0, stream>>>(ei, row_ptr, counts, srcs);

  k_prep<<<768, 256, 0, stream>>>(ggc_w, w_ih, w_hh, WcH, WcL, whhH, whhL, zbuf);
  k_lin0<<<8192, 256, 0, stream>>>(x, lin0_w, hf, h16);

  for (int L = 0; L < 4; ++L) {
    k_agg<<<8192, 256, 0, stream>>>(h16, mg, row_ptr, srcs);
    k_gru_mfma<<<256, 256, 0, stream>>>(mg, hf, h16,
                                        WcH + (size_t)L * 49152,
                                        WcL + (size_t)L * 49152,
                                        whhH, whhL, b_ih, b_hh, L < 3 ? 1 : 0);
  }

  k_musig<<<8192, 256, 0, stream>>>(hf, lin1_w, lin1_b, lin2_w, lin2_b, mu, sigma);
  k_sample<<<128, 256, 0, stream>>>(mu, sigma, zbuf, out);
}

// Round 14
// 340.222 us; speedup vs baseline: 1.2772x; 1.2772x over previous
//
#include <hip/hip_runtime.h>
#include <stdint.h>

#define N_NODES 32768
#define N_EDGES 524288
#define NODE_MASK (N_NODES - 1)

typedef __attribute__((ext_vector_type(8))) short bf16x8;
typedef __attribute__((ext_vector_type(4))) float f32x4;
typedef __attribute__((ext_vector_type(8))) _Float16 f16x8;
typedef unsigned short ushort_t;

__device__ __forceinline__ ushort_t f2b(float f) {  // f32 -> bf16 RNE
  uint32_t u = __float_as_uint(f);
  return (ushort_t)((u + 0x7FFFu + ((u >> 16) & 1u)) >> 16);
}
__device__ __forceinline__ float b2f(uint32_t lo16) {
  return __uint_as_float(lo16 << 16);
}

// split f32[8] -> (hi trunc, lo RNE) bf16x8 planes
__device__ __forceinline__ void split8(const float* __restrict__ p,
                                       bf16x8* H, bf16x8* L) {
  bf16x8 h, lo;
#pragma unroll
  for (int i = 0; i < 8; ++i) {
    float x = p[i];
    uint32_t u = __float_as_uint(x);
    ushort_t hb = (ushort_t)(u >> 16);                 // truncation split
    float r = x - __uint_as_float((uint32_t)hb << 16); // exact residual
    h[i] = (short)hb;
    lo[i] = (short)f2b(r);
  }
  *H = h; *L = lo;
}

// ---------------- threefry2x32 (Threefry-20, partitionable mode) ------------
__device__ __forceinline__ uint32_t rotl32(uint32_t v, int r) {
  return (v << r) | (v >> (32 - r));
}

__device__ __forceinline__ void threefry2x32(uint32_t k0, uint32_t k1,
                                             uint32_t x0, uint32_t x1,
                                             uint32_t* o0, uint32_t* o1) {
  uint32_t k2 = k0 ^ k1 ^ 0x1BD11BDAu;
  x0 += k0; x1 += k1;
  x0 += x1; x1 = rotl32(x1, 13); x1 ^= x0;
  x0 += x1; x1 = rotl32(x1, 15); x1 ^= x0;
  x0 += x1; x1 = rotl32(x1, 26); x1 ^= x0;
  x0 += x1; x1 = rotl32(x1,  6); x1 ^= x0;
  x0 += k1; x1 += k2 + 1u;
  x0 += x1; x1 = rotl32(x1, 17); x1 ^= x0;
  x0 += x1; x1 = rotl32(x1, 29); x1 ^= x0;
  x0 += x1; x1 = rotl32(x1, 16); x1 ^= x0;
  x0 += x1; x1 = rotl32(x1, 24); x1 ^= x0;
  x0 += k2; x1 += k0 + 2u;
  x0 += x1; x1 = rotl32(x1, 13); x1 ^= x0;
  x0 += x1; x1 = rotl32(x1, 15); x1 ^= x0;
  x0 += x1; x1 = rotl32(x1, 26); x1 ^= x0;
  x0 += x1; x1 = rotl32(x1,  6); x1 ^= x0;
  x0 += k0; x1 += k1 + 3u;
  x0 += x1; x1 = rotl32(x1, 17); x1 ^= x0;
  x0 += x1; x1 = rotl32(x1, 29); x1 ^= x0;
  x0 += x1; x1 = rotl32(x1, 16); x1 ^= x0;
  x0 += x1; x1 = rotl32(x1, 24); x1 ^= x0;
  x0 += k1; x1 += k2 + 4u;
  x0 += x1; x1 = rotl32(x1, 13); x1 ^= x0;
  x0 += x1; x1 = rotl32(x1, 15); x1 ^= x0;
  x0 += x1; x1 = rotl32(x1, 26); x1 ^= x0;
  x0 += x1; x1 = rotl32(x1,  6); x1 ^= x0;
  x0 += k2; x1 += k0 + 5u;
  *o0 = x0; *o1 = x1;
}

__device__ __forceinline__ float bits_to_normal(uint32_t b) {
  uint32_t fb = (b >> 9) | 0x3F800000u;
  float f = __uint_as_float(fb) - 1.0f;          // [0,1)
  const float LO = -0.99999994f;
  float u = f * 2.0f + LO;
  u = fmaxf(LO, u);
  double zd = 1.4142135623730951 * erfinv((double)u);
  return (float)zd;
}

// ---------------- zero helper ------------------------------------------------
__global__ void k_zero(int* __restrict__ p, int n) {
  for (int i = blockIdx.x * blockDim.x + threadIdx.x; i < n;
       i += gridDim.x * blockDim.x)
    p[i] = 0;
}

// ---------------- CSR build (edge_index int32) ------------------------------
__global__ void k_hist(const int* __restrict__ ei, int* __restrict__ counts) {
  for (int e = blockIdx.x * blockDim.x + threadIdx.x; e < N_EDGES;
       e += gridDim.x * blockDim.x)
    atomicAdd(&counts[ei[N_EDGES + e] & NODE_MASK], 1);
}

// scan + zero counts (cursor reuse) in one launch
__global__ __launch_bounds__(1024) void k_scan(int* __restrict__ counts,
                                               int* __restrict__ row_ptr) {
  __shared__ int part[1024];
  int t = threadIdx.x;
  const int CH = N_NODES / 1024;  // 32
  int base = t * CH;
  int s = 0;
  for (int i = 0; i < CH; ++i) s += counts[base + i];
  part[t] = s;
  __syncthreads();
  for (int off = 1; off < 1024; off <<= 1) {
    int add = (t >= off) ? part[t - off] : 0;
    __syncthreads();
    part[t] += add;
    __syncthreads();
  }
  int run = (t == 0) ? 0 : part[t - 1];
  for (int i = 0; i < CH; ++i) { row_ptr[base + i] = run; run += counts[base + i]; }
  if (t == 1023) row_ptr[N_NODES] = run;
  __syncthreads();
  for (int i = t; i < N_NODES; i += 1024) counts[i] = 0;  // cursor init
}

__global__ void k_fill(const int* __restrict__ ei, const int* __restrict__ row_ptr,
                       int* __restrict__ cursor, int* __restrict__ srcs) {
  for (int e = blockIdx.x * blockDim.x + threadIdx.x; e < N_EDGES;
       e += gridDim.x * blockDim.x) {
    int d = ei[N_EDGES + e] & NODE_MASK;
    int pos = row_ptr[d] + atomicAdd(&cursor[d], 1);
    srcs[pos] = ei[e] & NODE_MASK;
  }
}

// ---------------- merged prep: Wc combine + whh split + zgen ----------------
// Wc[L][c][k] = sum_j G[L][k][j]*w_ih[c][j]  (hi/lo bf16 planes)
__global__ __launch_bounds__(256) void k_prep(
    const float* __restrict__ G, const float* __restrict__ w_ih,
    const float* __restrict__ w_hh,
    ushort_t* __restrict__ WcH, ushort_t* __restrict__ WcL,
    ushort_t* __restrict__ whhH, ushort_t* __restrict__ whhL,
    float* __restrict__ z) {
  int i = blockIdx.x * 256 + threadIdx.x;
  if (i < 4 * 384 * 128) {
    int L = i / (384 * 128), r = i % (384 * 128);
    int c = r >> 7, k = r & 127;
    const float* g  = G + L * 16384 + k * 128;
    const float* wv = w_ih + c * 128;
    float acc = 0.f;
#pragma unroll 8
    for (int j = 0; j < 128; ++j) acc += g[j] * wv[j];
    ushort_t h = f2b(acc);
    WcH[i] = h; WcL[i] = f2b(acc - b2f(h));
  }
  if (i < 384 * 128) {
    float b = w_hh[i];
    ushort_t bh = f2b(b);
    whhH[i] = bh; whhL[i] = f2b(b - b2f(bh));
  }
  if (i < 32640) {
    uint32_t o0, o1;
    threefry2x32(0u, 123u, 0u, (uint32_t)i, &o0, &o1);
    z[i] = bits_to_normal(o0 ^ o1);
  }
}

// ---------------- lin0: hf (f32) + h16 (f16 shadow), padded to 128 ----------
__global__ __launch_bounds__(256) void k_lin0(const float* __restrict__ x,
                                              const float* __restrict__ w,
                                              float* __restrict__ hf,
                                              _Float16* __restrict__ h16) {
  __shared__ float sw[64][33];
  __shared__ float sx[4][32];
  int t = threadIdx.x;
  for (int e = t; e < 64 * 32; e += 256) sw[e >> 5][e & 31] = w[e];
  int node0 = blockIdx.x * 4;
  if (t < 128) sx[t >> 5][t & 31] = x[node0 * 32 + t];
  __syncthreads();
  int c = t & 63, nl = t >> 6;
  float acc = 0.f;
#pragma unroll
  for (int k = 0; k < 32; ++k) acc += sx[nl][k] * sw[c][k];
  float s = 1.f / (1.f + expf(-acc));
  int n = node0 + nl;
  hf[n * 128 + c] = s;
  hf[n * 128 + 64 + c] = 0.f;
  h16[n * 128 + c] = (_Float16)s;
  h16[n * 128 + 64 + c] = (_Float16)0.f;
}

// ---------------- segment-sum gather: 16B/lane, 4 edges/instr, f32 out ------
__global__ void k_agg(const _Float16* __restrict__ h16,
                      float* __restrict__ mg,
                      const int* __restrict__ row_ptr, const int* __restrict__ srcs) {
  int wid = (blockIdx.x * blockDim.x + threadIdx.x) >> 6;
  int lane = threadIdx.x & 63;
  if (wid >= N_NODES) return;
  int cg = lane & 15, eg = lane >> 4;
  int beg = row_ptr[wid], end = row_ptr[wid + 1];
  float acc[8];
#pragma unroll
  for (int i = 0; i < 8; ++i) acc[i] = 0.f;
  for (int e = beg + eg; e < end; e += 4) {
    int s = srcs[e] & NODE_MASK;
    f16x8 v = *(const f16x8*)&h16[s * 128 + cg * 8];
#pragma unroll
    for (int i = 0; i < 8; ++i) acc[i] += (float)v[i];
  }
#pragma unroll
  for (int i = 0; i < 8; ++i) {
    acc[i] += __shfl_xor(acc[i], 16);
    acc[i] += __shfl_xor(acc[i], 32);
  }
  if (eg == 0) {
    float4 lo = make_float4(acc[0], acc[1], acc[2], acc[3]);
    float4 hi = make_float4(acc[4], acc[5], acc[6], acc[7]);
    *(float4*)&mg[wid * 128 + cg * 8] = lo;
    *(float4*)&mg[wid * 128 + cg * 8 + 4] = hi;
  }
}

// ---------------- fused GRU via 3-term split MFMA (16 nodes/wave) -----------
// gi = hagg @ Wc^T (+b_ih), gh = h @ w_hh^T (+b_hh); Wc = G @ w_ih^T folded.
// Weights staged per ct via global_load_lds (linear LDS dest, pre-swizzled
// global source; read side applies the same XOR involution). h kept f32;
// epilogue refreshes the f16 gather shadow (skipped on last layer).
// NOTE (r13 lesson): 32 nodes/wave spills (A-frags alone = 128 VGPR); 16 is
// the register-feasible max with 4 A-operand sets.
__global__ __launch_bounds__(256, 2) void k_gru_mfma(
    const float* __restrict__ mg,
    float* __restrict__ hf, _Float16* __restrict__ h16,
    const ushort_t* __restrict__ WcH, const ushort_t* __restrict__ WcL,
    const ushort_t* __restrict__ whhH, const ushort_t* __restrict__ whhL,
    const float* __restrict__ b_ih, const float* __restrict__ b_hh,
    int writeShadow) {
  __shared__ __align__(16) char smem[49152];  // 12 slices x 4 KB
  int t = threadIdx.x;
  int w = t >> 6, l = t & 63;
  int node0 = blockIdx.x * 64 + w * 16;
  int ar = l & 15, hi = l >> 4, ak = hi * 8;
  bf16x8 amH[4], amL[4], ahH[4], ahL[4];
#pragma unroll
  for (int kk = 0; kk < 4; ++kk) {
    int o = (node0 + ar) * 128 + kk * 32 + ak;
    split8(&mg[o], &amH[kk], &amL[kk]);
    split8(&hf[o], &ahH[kk], &ahL[kk]);
  }
  // per-lane pre-swizzled global source pointers (12 x 1KB wave chunks / ct)
  const ushort_t* pq[12];
#pragma unroll
  for (int q = 0; q < 12; ++q) {
    int i = (q * 4 + w) * 64 + l;          // linear granule index in 48 KB
    int s = i >> 8, r = (i >> 4) & 15, gl = i & 15;
    int gsrc = gl ^ (r & 7);               // inverse of read-side XOR
    int mtx = s / 6, rem = s % 6, gate = rem >> 1, plane = rem & 1;
    const ushort_t* base = mtx ? (plane ? whhL : whhH) : (plane ? WcL : WcH);
    pq[q] = base + (gate * 128 + r) * 128 + gsrc * 8;
  }
  const char* lds = (const char*)smem;
  for (int ct = 0; ct < 8; ++ct) {
    int c0 = ct * 16;
    // async stage this ct's 48 KB of weights
#pragma unroll
    for (int q = 0; q < 12; ++q) {
      __builtin_amdgcn_global_load_lds(
          (const __attribute__((address_space(1))) void*)(pq[q] + c0 * 128),
          (__attribute__((address_space(3))) void*)(smem + (q * 4 + w) * 1024),
          16, 0, 0);
    }
    // prefetch previous-h (coalesced f32; own nodes/cols only)
    int col = c0 + ar;
    float hp[4];
#pragma unroll
    for (int j = 0; j < 4; ++j)
      hp[j] = hf[(node0 + hi * 4 + j) * 128 + col];
    __syncthreads();  // staging landed (compiler drains vmcnt before barrier)
    f32x4 air = {0.f,0.f,0.f,0.f}, aiz = air, ain = air;
    f32x4 ahr = air, ahz = air, ahn = air;
    int rbase = ar * 256;
    int rsw = (ar & 7) << 4;
#pragma unroll
    for (int kk = 0; kk < 4; ++kk) {
      int bin = rbase + ((kk * 64 + hi * 16) ^ rsw);
      bf16x8 B0  = *(const bf16x8*)(lds + 0 * 4096 + bin);
      bf16x8 B1  = *(const bf16x8*)(lds + 1 * 4096 + bin);
      bf16x8 B2  = *(const bf16x8*)(lds + 2 * 4096 + bin);
      bf16x8 B3  = *(const bf16x8*)(lds + 3 * 4096 + bin);
      bf16x8 B4  = *(const bf16x8*)(lds + 4 * 4096 + bin);
      bf16x8 B5  = *(const bf16x8*)(lds + 5 * 4096 + bin);
      bf16x8 B6  = *(const bf16x8*)(lds + 6 * 4096 + bin);
      bf16x8 B7  = *(const bf16x8*)(lds + 7 * 4096 + bin);
      bf16x8 B8  = *(const bf16x8*)(lds + 8 * 4096 + bin);
      bf16x8 B9  = *(const bf16x8*)(lds + 9 * 4096 + bin);
      bf16x8 B10 = *(const bf16x8*)(lds + 10 * 4096 + bin);
      bf16x8 B11 = *(const bf16x8*)(lds + 11 * 4096 + bin);
      air = __builtin_amdgcn_mfma_f32_16x16x32_bf16(amH[kk], B0,  air, 0, 0, 0);
      air = __builtin_amdgcn_mfma_f32_16x16x32_bf16(amH[kk], B1,  air, 0, 0, 0);
      air = __builtin_amdgcn_mfma_f32_16x16x32_bf16(amL[kk], B0,  air, 0, 0, 0);
      aiz = __builtin_amdgcn_mfma_f32_16x16x32_bf16(amH[kk], B2,  aiz, 0, 0, 0);
      aiz = __builtin_amdgcn_mfma_f32_16x16x32_bf16(amH[kk], B3,  aiz, 0, 0, 0);
      aiz = __builtin_amdgcn_mfma_f32_16x16x32_bf16(amL[kk], B2,  aiz, 0, 0, 0);
      ain = __builtin_amdgcn_mfma_f32_16x16x32_bf16(amH[kk], B4,  ain, 0, 0, 0);
      ain = __builtin_amdgcn_mfma_f32_16x16x32_bf16(amH[kk], B5,  ain, 0, 0, 0);
      ain = __builtin_amdgcn_mfma_f32_16x16x32_bf16(amL[kk], B4,  ain, 0, 0, 0);
      ahr = __builtin_amdgcn_mfma_f32_16x16x32_bf16(ahH[kk], B6,  ahr, 0, 0, 0);
      ahr = __builtin_amdgcn_mfma_f32_16x16x32_bf16(ahH[kk], B7,  ahr, 0, 0, 0);
      ahr = __builtin_amdgcn_mfma_f32_16x16x32_bf16(ahL[kk], B6,  ahr, 0, 0, 0);
      ahz = __builtin_amdgcn_mfma_f32_16x16x32_bf16(ahH[kk], B8,  ahz, 0, 0, 0);
      ahz = __builtin_amdgcn_mfma_f32_16x16x32_bf16(ahH[kk], B9,  ahz, 0, 0, 0);
      ahz = __builtin_amdgcn_mfma_f32_16x16x32_bf16(ahL[kk], B8,  ahz, 0, 0, 0);
      ahn = __builtin_amdgcn_mfma_f32_16x16x32_bf16(ahH[kk], B10, ahn, 0, 0, 0);
      ahn = __builtin_amdgcn_mfma_f32_16x16x32_bf16(ahH[kk], B11, ahn, 0, 0, 0);
      ahn = __builtin_amdgcn_mfma_f32_16x16x32_bf16(ahL[kk], B10, ahn, 0, 0, 0);
    }
    float bir = b_ih[col], biz = b_ih[128 + col], bin = b_ih[256 + col];
    float bhr = b_hh[col], bhz = b_hh[128 + col], bhn = b_hh[256 + col];
#pragma unroll
    for (int j = 0; j < 4; ++j) {
      int idx = (node0 + hi * 4 + j) * 128 + col;
      float gr = air[j] + bir + ahr[j] + bhr;
      float gz = aiz[j] + biz + ahz[j] + bhz;
      float r  = 1.f / (1.f + expf(-gr));
      float zg = 1.f / (1.f + expf(-gz));
      float nn = tanhf(ain[j] + bin + r * (ahn[j] + bhn));
      float hn = (1.f - zg) * nn + zg * hp[j];
      hf[idx] = hn;
      if (writeShadow) h16[idx] = (_Float16)hn;
    }
    __syncthreads();  // all LDS reads done before next ct restages
  }
}

// ---------------- heads (f32 hf) ---------------------------------------------
__global__ __launch_bounds__(256) void k_musig(const float* __restrict__ hf,
                                               const float* __restrict__ w1,
                                               const float* __restrict__ b1,
                                               const float* __restrict__ w2,
                                               const float* __restrict__ b2,
                                               float* __restrict__ mu,
                                               float* __restrict__ sigma) {
  int t = threadIdx.x;
  int lane = t & 63, wv = t >> 6;
  int n = blockIdx.x * 4 + wv;
  float2 hv = *(const float2*)&hf[n * 128 + lane * 2];
  hv.x = fmaxf(hv.x, 0.f); hv.y = fmaxf(hv.y, 0.f);
  float2 w1v = *(const float2*)&w1[lane * 2];
  float2 w2v = *(const float2*)&w2[lane * 2];
  float a = hv.x * w1v.x + hv.y * w1v.y;
  float b = hv.x * w2v.x + hv.y * w2v.y;
#pragma unroll
  for (int off = 32; off > 0; off >>= 1) {
    a += __shfl_down(a, off);
    b += __shfl_down(b, off);
  }
  if (lane == 0) {
    mu[n] = a + b1[0];
    float v = b + b2[0];
    sigma[n] = fmaxf(v, 0.f) + log1pf(expf(-fabsf(v)));
  }
}

// ---------------- sampler (fp64 internal): analytic Cholesky ----------------
__device__ __forceinline__ double dscan_incl(double v, volatile double* buf, int i,
                                             double* tot) {
  buf[i] = v;
  __syncthreads();
#pragma unroll
  for (int off = 1; off < 256; off <<= 1) {
    double add = (i >= off) ? buf[i - off] : 0.0;
    __syncthreads();
    buf[i] += add;
    __syncthreads();
  }
  double incl = buf[i];
  *tot = buf[255];
  __syncthreads();
  return incl;
}

__global__ __launch_bounds__(256) void k_sample(const float* __restrict__ mu,
                                                const float* __restrict__ sigma,
                                                const float* __restrict__ zbuf,
                                                float* __restrict__ out) {
  __shared__ double buf[256];
  __shared__ double lastd[2];
  int g = blockIdx.x, i = threadIdx.x;
  int n = (g << 8) + i;
  double sig = (double)sigma[n], muv = (double)mu[n];
  bool isLast = (i == 255);
  if (isLast) { lastd[0] = sig; lastd[1] = muv; }
  double s   = isLast ? 0.0 : sig;
  double mui = isLast ? 0.0 : muv;
  double tS, tM, tY, tX;
  double inclS = dscan_incl(s, buf, i, &tS);
  dscan_incl(mui, buf, i, &tM);
  double sigLast = lastd[0], muLast = lastd[1];
  double denom = tS + sigLast;
  double c = -muLast / sigLast;
  double pre = inclS - s;
  double suffix  = denom - pre;
  double suffix1 = suffix - s;
  double sigL = isLast ? 0.0 : sqrt(s * suffix1 / suffix);
  double cL   = isLast ? 0.0 : (-s / (suffix * sigL));
  double zv   = isLast ? 0.0 : (double)zbuf[g * 255 + i];
  double y = cL * zv;
  double inclY = dscan_incl(y, buf, i, &tY);
  double Pz = inclY - y;
  double rm = s * c + mui - s * (c * tS + tM) / denom;
  double X = rm + s * Pz + sigL * zv;
  if (isLast) X = 0.0;
  dscan_incl(X, buf, i, &tX);
  out[n] = (float)(isLast ? (0.0 - tX) : X);
}

// ---------------------------------------------------------------------------
extern "C" void kernel_launch(void* const* d_in, const int* in_sizes, int n_in,
                              void* d_out, int out_size, void* d_ws, size_t ws_size,
                              hipStream_t stream) {
  const float* x      = (const float*)d_in[0];
  const float* lin0_w = (const float*)d_in[1];
  const float* ggc_w  = (const float*)d_in[2];
  const float* w_ih   = (const float*)d_in[3];
  const float* w_hh   = (const float*)d_in[4];
  const float* b_ih   = (const float*)d_in[5];
  const float* b_hh   = (const float*)d_in[6];
  const float* lin1_w = (const float*)d_in[7];
  const float* lin1_b = (const float*)d_in[8];
  const float* lin2_w = (const float*)d_in[9];
  const float* lin2_b = (const float*)d_in[10];
  const int*   ei     = (const int*)d_in[11];
  float* out = (float*)d_out;

  char* ws = (char*)d_ws;
  float*    hf     = (float*)   (ws + 0);          // 16 MB (f32 master h)
  _Float16* h16    = (_Float16*)(ws + 16777216);   // 8 MB (f16 gather shadow)
  float*    mg     = (float*)   (ws + 25165824);   // 16 MB (f32 hagg)
  ushort_t* WcH    = (ushort_t*)(ws + 41943040);   // 384 KB (4 layers)
  ushort_t* WcL    = (ushort_t*)(ws + 42336256);   // 384 KB
  ushort_t* whhH   = (ushort_t*)(ws + 42729472);   // 96 KB
  ushort_t* whhL   = (ushort_t*)(ws + 42827776);   // 96 KB
  float*    zbuf   = (float*)   (ws + 42926080);   // 128 KB [counts aliases]
  float*    mu     = (float*)   (ws + 43057152);   // 128 KB
  float*    sigma  = (float*)   (ws + 43188224);   // 128 KB
  int*      row_ptr= (int*)     (ws + 43319296);   // 128.5 KB slot
  int*      srcs   = (int*)     (ws + 43450880);   // 2 MB -> ends 45548032
  int*      counts = (int*)zbuf;                   // alias: CSR before k_prep z
  const size_t WS_NEEDED = 45548032;               // < proven 53477888
  if (ws_size < WS_NEEDED) return;

  // CSR build (counts aliases zbuf; zgen output written later by k_prep)
  k_zero<<<32, 256, 0, stream>>>(counts, N_NODES);
  k_hist<<<1024, 256, 0, stream>>>(ei, counts);
  k_scan<<<1, 1024, 0, stream>>>(counts, row_ptr);   // also re-zeros counts
  k_fill<<<1024, 256, 0, stream>>>(ei, row_ptr, counts, srcs);

  k_prep<<<768, 256, 0, stream>>>(ggc_w, w_ih, w_hh, WcH, WcL, whhH, whhL, zbuf);
  k_lin0<<<8192, 256, 0, stream>>>(x, lin0_w, hf, h16);

  for (int L = 0; L < 4; ++L) {
    k_agg<<<8192, 256, 0, stream>>>(h16, mg, row_ptr, srcs);
    k_gru_mfma<<<512, 256, 0, stream>>>(mg, hf, h16,
                                        WcH + (size_t)L * 49152,
                                        WcL + (size_t)L * 49152,
                                        whhH, whhL, b_ih, b_hh, L < 3 ? 1 : 0);
  }

  k_musig<<<8192, 256, 0, stream>>>(hf, lin1_w, lin1_b, lin2_w, lin2_b, mu, sigma);
  k_sample<<<128, 256, 0, stream>>>(mu, sigma, zbuf, out);
}

// Round 15
// 321.645 us; speedup vs baseline: 1.3509x; 1.0578x over previous
//
#include <hip/hip_runtime.h>
#include <stdint.h>

#define N_NODES 32768
#define N_EDGES 524288
#define NODE_MASK (N_NODES - 1)

typedef __attribute__((ext_vector_type(8))) short bf16x8;
typedef __attribute__((ext_vector_type(4))) float f32x4;
typedef __attribute__((ext_vector_type(8))) _Float16 f16x8;
typedef unsigned short ushort_t;

__device__ __forceinline__ ushort_t f2b(float f) {  // f32 -> bf16 RNE
  uint32_t u = __float_as_uint(f);
  return (ushort_t)((u + 0x7FFFu + ((u >> 16) & 1u)) >> 16);
}
__device__ __forceinline__ float b2f(uint32_t lo16) {
  return __uint_as_float(lo16 << 16);
}

// split f32[8] -> (hi, lo) f16x8 planes; hi = f16(x), lo = f16(x - hi).
// Combined 2-term representation is exact to ~2^-22 relative.
__device__ __forceinline__ void split8f(const float* __restrict__ p,
                                        f16x8* H, f16x8* L) {
  f16x8 h, lo;
#pragma unroll
  for (int i = 0; i < 8; ++i) {
    float x = p[i];
    _Float16 hh = (_Float16)x;        // RNE
    float r = x - (float)hh;          // exact residual
    h[i] = hh;
    lo[i] = (_Float16)r;
  }
  *H = h; *L = lo;
}

// ---------------- threefry2x32 (Threefry-20, partitionable mode) ------------
__device__ __forceinline__ uint32_t rotl32(uint32_t v, int r) {
  return (v << r) | (v >> (32 - r));
}

__device__ __forceinline__ void threefry2x32(uint32_t k0, uint32_t k1,
                                             uint32_t x0, uint32_t x1,
                                             uint32_t* o0, uint32_t* o1) {
  uint32_t k2 = k0 ^ k1 ^ 0x1BD11BDAu;
  x0 += k0; x1 += k1;
  x0 += x1; x1 = rotl32(x1, 13); x1 ^= x0;
  x0 += x1; x1 = rotl32(x1, 15); x1 ^= x0;
  x0 += x1; x1 = rotl32(x1, 26); x1 ^= x0;
  x0 += x1; x1 = rotl32(x1,  6); x1 ^= x0;
  x0 += k1; x1 += k2 + 1u;
  x0 += x1; x1 = rotl32(x1, 17); x1 ^= x0;
  x0 += x1; x1 = rotl32(x1, 29); x1 ^= x0;
  x0 += x1; x1 = rotl32(x1, 16); x1 ^= x0;
  x0 += x1; x1 = rotl32(x1, 24); x1 ^= x0;
  x0 += k2; x1 += k0 + 2u;
  x0 += x1; x1 = rotl32(x1, 13); x1 ^= x0;
  x0 += x1; x1 = rotl32(x1, 15); x1 ^= x0;
  x0 += x1; x1 = rotl32(x1, 26); x1 ^= x0;
  x0 += x1; x1 = rotl32(x1,  6); x1 ^= x0;
  x0 += k0; x1 += k1 + 3u;
  x0 += x1; x1 = rotl32(x1, 17); x1 ^= x0;
  x0 += x1; x1 = rotl32(x1, 29); x1 ^= x0;
  x0 += x1; x1 = rotl32(x1, 16); x1 ^= x0;
  x0 += x1; x1 = rotl32(x1, 24); x1 ^= x0;
  x0 += k1; x1 += k2 + 4u;
  x0 += x1; x1 = rotl32(x1, 13); x1 ^= x0;
  x0 += x1; x1 = rotl32(x1, 15); x1 ^= x0;
  x0 += x1; x1 = rotl32(x1, 26); x1 ^= x0;
  x0 += x1; x1 = rotl32(x1,  6); x1 ^= x0;
  x0 += k2; x1 += k0 + 5u;
  *o0 = x0; *o1 = x1;
}

__device__ __forceinline__ float bits_to_normal(uint32_t b) {
  uint32_t fb = (b >> 9) | 0x3F800000u;
  float f = __uint_as_float(fb) - 1.0f;          // [0,1)
  const float LO = -0.99999994f;
  float u = f * 2.0f + LO;
  u = fmaxf(LO, u);
  double zd = 1.4142135623730951 * erfinv((double)u);
  return (float)zd;
}

// ---------------- zero helper ------------------------------------------------
__global__ void k_zero(int* __restrict__ p, int n) {
  for (int i = blockIdx.x * blockDim.x + threadIdx.x; i < n;
       i += gridDim.x * blockDim.x)
    p[i] = 0;
}

// ---------------- CSR build (edge_index int32) ------------------------------
__global__ void k_hist(const int* __restrict__ ei, int* __restrict__ counts) {
  for (int e = blockIdx.x * blockDim.x + threadIdx.x; e < N_EDGES;
       e += gridDim.x * blockDim.x)
    atomicAdd(&counts[ei[N_EDGES + e] & NODE_MASK], 1);
}

// scan + zero counts (cursor reuse) in one launch
__global__ __launch_bounds__(1024) void k_scan(int* __restrict__ counts,
                                               int* __restrict__ row_ptr) {
  __shared__ int part[1024];
  int t = threadIdx.x;
  const int CH = N_NODES / 1024;  // 32
  int base = t * CH;
  int s = 0;
  for (int i = 0; i < CH; ++i) s += counts[base + i];
  part[t] = s;
  __syncthreads();
  for (int off = 1; off < 1024; off <<= 1) {
    int add = (t >= off) ? part[t - off] : 0;
    __syncthreads();
    part[t] += add;
    __syncthreads();
  }
  int run = (t == 0) ? 0 : part[t - 1];
  for (int i = 0; i < CH; ++i) { row_ptr[base + i] = run; run += counts[base + i]; }
  if (t == 1023) row_ptr[N_NODES] = run;
  __syncthreads();
  for (int i = t; i < N_NODES; i += 1024) counts[i] = 0;  // cursor init
}

__global__ void k_fill(const int* __restrict__ ei, const int* __restrict__ row_ptr,
                       int* __restrict__ cursor, int* __restrict__ srcs) {
  for (int e = blockIdx.x * blockDim.x + threadIdx.x; e < N_EDGES;
       e += gridDim.x * blockDim.x) {
    int d = ei[N_EDGES + e] & NODE_MASK;
    int pos = row_ptr[d] + atomicAdd(&cursor[d], 1);
    srcs[pos] = ei[e] & NODE_MASK;
  }
}

// ---------------- merged prep: Wc combine (f16) + whh (f16) + zgen ----------
// Wc[L][c][k] = sum_j G[L][k][j]*w_ih[c][j]; single f16 plane (weights are
// O(0.1): f16 rel err 2^-11, SYSTEMATIC across nodes -> behaves as a tiny
// weight perturbation, not per-node noise).
__global__ __launch_bounds__(256) void k_prep(
    const float* __restrict__ G, const float* __restrict__ w_ih,
    const float* __restrict__ w_hh,
    _Float16* __restrict__ WcF, _Float16* __restrict__ whhF,
    float* __restrict__ z) {
  int i = blockIdx.x * 256 + threadIdx.x;
  if (i < 4 * 384 * 128) {
    int L = i / (384 * 128), r = i % (384 * 128);
    int c = r >> 7, k = r & 127;
    const float* g  = G + L * 16384 + k * 128;
    const float* wv = w_ih + c * 128;
    float acc = 0.f;
#pragma unroll 8
    for (int j = 0; j < 128; ++j) acc += g[j] * wv[j];
    WcF[i] = (_Float16)acc;
  }
  if (i < 384 * 128) {
    whhF[i] = (_Float16)w_hh[i];
  }
  if (i < 32640) {
    uint32_t o0, o1;
    threefry2x32(0u, 123u, 0u, (uint32_t)i, &o0, &o1);
    z[i] = bits_to_normal(o0 ^ o1);
  }
}

// ---------------- lin0: hf (f32) + h16 (f16 shadow), padded to 128 ----------
__global__ __launch_bounds__(256) void k_lin0(const float* __restrict__ x,
                                              const float* __restrict__ w,
                                              float* __restrict__ hf,
                                              _Float16* __restrict__ h16) {
  __shared__ float sw[64][33];
  __shared__ float sx[4][32];
  int t = threadIdx.x;
  for (int e = t; e < 64 * 32; e += 256) sw[e >> 5][e & 31] = w[e];
  int node0 = blockIdx.x * 4;
  if (t < 128) sx[t >> 5][t & 31] = x[node0 * 32 + t];
  __syncthreads();
  int c = t & 63, nl = t >> 6;
  float acc = 0.f;
#pragma unroll
  for (int k = 0; k < 32; ++k) acc += sx[nl][k] * sw[c][k];
  float s = 1.f / (1.f + expf(-acc));
  int n = node0 + nl;
  hf[n * 128 + c] = s;
  hf[n * 128 + 64 + c] = 0.f;
  h16[n * 128 + c] = (_Float16)s;
  h16[n * 128 + 64 + c] = (_Float16)0.f;
}

// ---------------- segment-sum gather: 16B/lane, 4 edges/instr, f32 out ------
__global__ void k_agg(const _Float16* __restrict__ h16,
                      float* __restrict__ mg,
                      const int* __restrict__ row_ptr, const int* __restrict__ srcs) {
  int wid = (blockIdx.x * blockDim.x + threadIdx.x) >> 6;
  int lane = threadIdx.x & 63;
  if (wid >= N_NODES) return;
  int cg = lane & 15, eg = lane >> 4;
  int beg = row_ptr[wid], end = row_ptr[wid + 1];
  float acc[8];
#pragma unroll
  for (int i = 0; i < 8; ++i) acc[i] = 0.f;
  for (int e = beg + eg; e < end; e += 4) {
    int s = srcs[e] & NODE_MASK;
    f16x8 v = *(const f16x8*)&h16[s * 128 + cg * 8];
#pragma unroll
    for (int i = 0; i < 8; ++i) acc[i] += (float)v[i];
  }
#pragma unroll
  for (int i = 0; i < 8; ++i) {
    acc[i] += __shfl_xor(acc[i], 16);
    acc[i] += __shfl_xor(acc[i], 32);
  }
  if (eg == 0) {
    float4 lo = make_float4(acc[0], acc[1], acc[2], acc[3]);
    float4 hi = make_float4(acc[4], acc[5], acc[6], acc[7]);
    *(float4*)&mg[wid * 128 + cg * 8] = lo;
    *(float4*)&mg[wid * 128 + cg * 8 + 4] = hi;
  }
}

// ---------------- fused GRU via 2-term f16 MFMA (16 nodes/wave) -------------
// gi = hagg @ Wc^T (+b_ih), gh = h @ w_hh^T (+b_hh). Activations are 2-term
// f16 (hi+lo, exact to 2^-22); weights single f16 plane. 6 slices x 4 KB
// staged per ct via global_load_lds (linear dest, pre-swizzled source).
// NOTE (r13 lesson): 16 nodes/wave is the register-feasible max.
__global__ __launch_bounds__(256, 2) void k_gru_mfma(
    const float* __restrict__ mg,
    float* __restrict__ hf, _Float16* __restrict__ h16,
    const _Float16* __restrict__ WcF, const _Float16* __restrict__ whhF,
    const float* __restrict__ b_ih, const float* __restrict__ b_hh,
    int writeShadow) {
  __shared__ __align__(16) char smem[24576];  // 6 slices x 4 KB
  int t = threadIdx.x;
  int w = t >> 6, l = t & 63;
  int node0 = blockIdx.x * 64 + w * 16;
  int ar = l & 15, hi = l >> 4, ak = hi * 8;
  f16x8 amH[4], amL[4], ahH[4], ahL[4];
#pragma unroll
  for (int kk = 0; kk < 4; ++kk) {
    int o = (node0 + ar) * 128 + kk * 32 + ak;
    split8f(&mg[o], &amH[kk], &amL[kk]);
    split8f(&hf[o], &ahH[kk], &ahL[kk]);
  }
  // per-lane pre-swizzled global source pointers (6 x 1KB wave chunks / ct)
  const _Float16* pq[6];
#pragma unroll
  for (int q = 0; q < 6; ++q) {
    int i = (q * 4 + w) * 64 + l;          // linear granule index in 24 KB
    int s = i >> 8, r = (i >> 4) & 15, gl = i & 15;
    int gsrc = gl ^ (r & 7);               // inverse of read-side XOR
    int mtx = s / 3, gate = s % 3;
    const _Float16* base = mtx ? whhF : WcF;
    pq[q] = base + (gate * 128 + r) * 128 + gsrc * 8;
  }
  const char* lds = (const char*)smem;
  for (int ct = 0; ct < 8; ++ct) {
    int c0 = ct * 16;
    // async stage this ct's 24 KB of weights
#pragma unroll
    for (int q = 0; q < 6; ++q) {
      __builtin_amdgcn_global_load_lds(
          (const __attribute__((address_space(1))) void*)(pq[q] + c0 * 128),
          (__attribute__((address_space(3))) void*)(smem + (q * 4 + w) * 1024),
          16, 0, 0);
    }
    // prefetch previous-h (coalesced f32; own nodes/cols only)
    int col = c0 + ar;
    float hp[4];
#pragma unroll
    for (int j = 0; j < 4; ++j)
      hp[j] = hf[(node0 + hi * 4 + j) * 128 + col];
    __syncthreads();  // staging landed (compiler drains vmcnt before barrier)
    f32x4 air = {0.f,0.f,0.f,0.f}, aiz = air, ain = air;
    f32x4 ahr = air, ahz = air, ahn = air;
    int rbase = ar * 256;
    int rsw = (ar & 7) << 4;
#pragma unroll
    for (int kk = 0; kk < 4; ++kk) {
      int bin = rbase + ((kk * 64 + hi * 16) ^ rsw);
      f16x8 W0 = *(const f16x8*)(lds + 0 * 4096 + bin);  // Wc r
      f16x8 W1 = *(const f16x8*)(lds + 1 * 4096 + bin);  // Wc z
      f16x8 W2 = *(const f16x8*)(lds + 2 * 4096 + bin);  // Wc n
      f16x8 W3 = *(const f16x8*)(lds + 3 * 4096 + bin);  // whh r
      f16x8 W4 = *(const f16x8*)(lds + 4 * 4096 + bin);  // whh z
      f16x8 W5 = *(const f16x8*)(lds + 5 * 4096 + bin);  // whh n
      air = __builtin_amdgcn_mfma_f32_16x16x32_f16(amH[kk], W0, air, 0, 0, 0);
      air = __builtin_amdgcn_mfma_f32_16x16x32_f16(amL[kk], W0, air, 0, 0, 0);
      aiz = __builtin_amdgcn_mfma_f32_16x16x32_f16(amH[kk], W1, aiz, 0, 0, 0);
      aiz = __builtin_amdgcn_mfma_f32_16x16x32_f16(amL[kk], W1, aiz, 0, 0, 0);
      ain = __builtin_amdgcn_mfma_f32_16x16x32_f16(amH[kk], W2, ain, 0, 0, 0);
      ain = __builtin_amdgcn_mfma_f32_16x16x32_f16(amL[kk], W2, ain, 0, 0, 0);
      ahr = __builtin_amdgcn_mfma_f32_16x16x32_f16(ahH[kk], W3, ahr, 0, 0, 0);
      ahr = __builtin_amdgcn_mfma_f32_16x16x32_f16(ahL[kk], W3, ahr, 0, 0, 0);
      ahz = __builtin_amdgcn_mfma_f32_16x16x32_f16(ahH[kk], W4, ahz, 0, 0, 0);
      ahz = __builtin_amdgcn_mfma_f32_16x16x32_f16(ahL[kk], W4, ahz, 0, 0, 0);
      ahn = __builtin_amdgcn_mfma_f32_16x16x32_f16(ahH[kk], W5, ahn, 0, 0, 0);
      ahn = __builtin_amdgcn_mfma_f32_16x16x32_f16(ahL[kk], W5, ahn, 0, 0, 0);
    }
    float bir = b_ih[col], biz = b_ih[128 + col], bin = b_ih[256 + col];
    float bhr = b_hh[col], bhz = b_hh[128 + col], bhn = b_hh[256 + col];
#pragma unroll
    for (int j = 0; j < 4; ++j) {
      int idx = (node0 + hi * 4 + j) * 128 + col;
      float gr = air[j] + bir + ahr[j] + bhr;
      float gz = aiz[j] + biz + ahz[j] + bhz;
      float r  = 1.f / (1.f + expf(-gr));
      float zg = 1.f / (1.f + expf(-gz));
      float nn = tanhf(ain[j] + bin + r * (ahn[j] + bhn));
      float hn = (1.f - zg) * nn + zg * hp[j];
      hf[idx] = hn;
      if (writeShadow) h16[idx] = (_Float16)hn;
    }
    __syncthreads();  // all LDS reads done before next ct restages
  }
}

// ---------------- heads (f32 hf) ---------------------------------------------
__global__ __launch_bounds__(256) void k_musig(const float* __restrict__ hf,
                                               const float* __restrict__ w1,
                                               const float* __restrict__ b1,
                                               const float* __restrict__ w2,
                                               const float* __restrict__ b2,
                                               float* __restrict__ mu,
                                               float* __restrict__ sigma) {
  int t = threadIdx.x;
  int lane = t & 63, wv = t >> 6;
  int n = blockIdx.x * 4 + wv;
  float2 hv = *(const float2*)&hf[n * 128 + lane * 2];
  hv.x = fmaxf(hv.x, 0.f); hv.y = fmaxf(hv.y, 0.f);
  float2 w1v = *(const float2*)&w1[lane * 2];
  float2 w2v = *(const float2*)&w2[lane * 2];
  float a = hv.x * w1v.x + hv.y * w1v.y;
  float b = hv.x * w2v.x + hv.y * w2v.y;
#pragma unroll
  for (int off = 32; off > 0; off >>= 1) {
    a += __shfl_down(a, off);
    b += __shfl_down(b, off);
  }
  if (lane == 0) {
    mu[n] = a + b1[0];
    float v = b + b2[0];
    sigma[n] = fmaxf(v, 0.f) + log1pf(expf(-fabsf(v)));
  }
}

// ---------------- sampler (fp64 internal): analytic Cholesky ----------------
__device__ __forceinline__ double dscan_incl(double v, volatile double* buf, int i,
                                             double* tot) {
  buf[i] = v;
  __syncthreads();
#pragma unroll
  for (int off = 1; off < 256; off <<= 1) {
    double add = (i >= off) ? buf[i - off] : 0.0;
    __syncthreads();
    buf[i] += add;
    __syncthreads();
  }
  double incl = buf[i];
  *tot = buf[255];
  __syncthreads();
  return incl;
}

__global__ __launch_bounds__(256) void k_sample(const float* __restrict__ mu,
                                                const float* __restrict__ sigma,
                                                const float* __restrict__ zbuf,
                                                float* __restrict__ out) {
  __shared__ double buf[256];
  __shared__ double lastd[2];
  int g = blockIdx.x, i = threadIdx.x;
  int n = (g << 8) + i;
  double sig = (double)sigma[n], muv = (double)mu[n];
  bool isLast = (i == 255);
  if (isLast) { lastd[0] = sig; lastd[1] = muv; }
  double s   = isLast ? 0.0 : sig;
  double mui = isLast ? 0.0 : muv;
  double tS, tM, tY, tX;
  double inclS = dscan_incl(s, buf, i, &tS);
  dscan_incl(mui, buf, i, &tM);
  double sigLast = lastd[0], muLast = lastd[1];
  double denom = tS + sigLast;
  double c = -muLast / sigLast;
  double pre = inclS - s;
  double suffix  = denom - pre;
  double suffix1 = suffix - s;
  double sigL = isLast ? 0.0 : sqrt(s * suffix1 / suffix);
  double cL   = isLast ? 0.0 : (-s / (suffix * sigL));
  double zv   = isLast ? 0.0 : (double)zbuf[g * 255 + i];
  double y = cL * zv;
  double inclY = dscan_incl(y, buf, i, &tY);
  double Pz = inclY - y;
  double rm = s * c + mui - s * (c * tS + tM) / denom;
  double X = rm + s * Pz + sigL * zv;
  if (isLast) X = 0.0;
  dscan_incl(X, buf, i, &tX);
  out[n] = (float)(isLast ? (0.0 - tX) : X);
}

// ---------------------------------------------------------------------------
extern "C" void kernel_launch(void* const* d_in, const int* in_sizes, int n_in,
                              void* d_out, int out_size, void* d_ws, size_t ws_size,
                              hipStream_t stream) {
  const float* x      = (const float*)d_in[0];
  const float* lin0_w = (const float*)d_in[1];
  const float* ggc_w  = (const float*)d_in[2];
  const float* w_ih   = (const float*)d_in[3];
  const float* w_hh   = (const float*)d_in[4];
  const float* b_ih   = (const float*)d_in[5];
  const float* b_hh   = (const float*)d_in[6];
  const float* lin1_w = (const float*)d_in[7];
  const float* lin1_b = (const float*)d_in[8];
  const float* lin2_w = (const float*)d_in[9];
  const float* lin2_b = (const float*)d_in[10];
  const int*   ei     = (const int*)d_in[11];
  float* out = (float*)d_out;

  char* ws = (char*)d_ws;
  float*     hf     = (float*)    (ws + 0);          // 16 MB (f32 master h)
  _Float16*  h16    = (_Float16*) (ws + 16777216);   // 8 MB (f16 gather shadow)
  float*     mg     = (float*)    (ws + 25165824);   // 16 MB (f32 hagg)
  _Float16*  WcF    = (_Float16*) (ws + 41943040);   // 384 KB (4 layers, f16)
  _Float16*  whhF   = (_Float16*) (ws + 42336256);   // 96 KB (f16)
  float*     zbuf   = (float*)    (ws + 42434560);   // 128 KB [counts aliases]
  float*     mu     = (float*)    (ws + 42565632);   // 128 KB
  float*     sigma  = (float*)    (ws + 42696704);   // 128 KB
  int*       row_ptr= (int*)      (ws + 42827776);   // 128.5 KB slot
  int*       srcs   = (int*)      (ws + 42959872);   // 2 MB -> ends 45057024
  int*       counts = (int*)zbuf;                    // alias: CSR before k_prep z
  const size_t WS_NEEDED = 45057024;                 // < proven 53477888
  if (ws_size < WS_NEEDED) return;

  // CSR build (counts aliases zbuf; zgen output written later by k_prep)
  k_zero<<<32, 256, 0, stream>>>(counts, N_NODES);
  k_hist<<<1024, 256, 0, stream>>>(ei, counts);
  k_scan<<<1, 1024, 0, stream>>>(counts, row_ptr);   // also re-zeros counts
  k_fill<<<1024, 256, 0, stream>>>(ei, row_ptr, counts, srcs);

  k_prep<<<768, 256, 0, stream>>>(ggc_w, w_ih, w_hh, WcF, whhF, zbuf);
  k_lin0<<<8192, 256, 0, stream>>>(x, lin0_w, hf, h16);

  for (int L = 0; L < 4; ++L) {
    k_agg<<<8192, 256, 0, stream>>>(h16, mg, row_ptr, srcs);
    k_gru_mfma<<<512, 256, 0, stream>>>(mg, hf, h16,
                                        WcF + (size_t)L * 49152,
                                        whhF, b_ih, b_hh, L < 3 ? 1 : 0);
  }

  k_musig<<<8192, 256, 0, stream>>>(hf, lin1_w, lin1_b, lin2_w, lin2_b, mu, sigma);
  k_sample<<<128, 256, 0, stream>>>(mu, sigma, zbuf, out);
}